// Round 1
// baseline (92.700 us; speedup 1.0000x reference)
//
#include <hip/hip_runtime.h>

// Problem constants (x: [128, 65536] fp32, LEVEL=8)
static constexpr int BROWS = 128;   // batch rows
static constexpr int T     = 65536; // samples per row
static constexpr int CL    = 256;   // chunk length = 2^LEVEL
static constexpr int NCH   = 256;   // chunks per row = T / CL (positions per node)
static constexpr int NODES = 256;   // 2^LEVEL leaves
static constexpr int KG    = 32;    // chunks handled per block in wht_kernel
static constexpr int LSTR  = 257;   // padded LDS row stride (breaks bank conflicts)

// Output row for Hadamard-order index h:
//   c_nat[n] = H[bitrev8(n)],  freq perm: out[m] = c_nat[gray^-1(m)]
//   => m = gray(bitrev8(h))
__device__ __forceinline__ int freq_pos(int h) {
    unsigned r = __brev((unsigned)h) >> 24; // bitrev8
    return (int)(r ^ (r >> 1));             // gray code
}

__global__ __launch_bounds__(256) void wht_kernel(const float* __restrict__ x,
                                                  float* __restrict__ coeffs) {
    __shared__ float lds[KG][LSTR];

    const int b    = blockIdx.x >> 3;  // 8 chunk-groups per row
    const int kg   = blockIdx.x & 7;
    const int k0   = kg * KG;
    const int lane = threadIdx.x & 63;
    const int wave = threadIdx.x >> 6; // 4 waves

    const float* xb = x + (size_t)b * T;

    // Each wave computes 8 chunks; lane holds elements j = 4*lane + {0,1,2,3}
    #pragma unroll
    for (int c = 0; c < KG / 4; ++c) {
        const int kl = wave * (KG / 4) + c; // local chunk row in LDS
        float4 v = *(const float4*)(xb + (size_t)(k0 + kl) * CL + lane * 4);

        // FWHT stage j^1 (intra-lane)
        float4 w;
        w.x = v.x + v.y; w.y = v.x - v.y;
        w.z = v.z + v.w; w.w = v.z - v.w;
        // FWHT stage j^2 (intra-lane)
        v.x = w.x + w.z; v.z = w.x - w.z;
        v.y = w.y + w.w; v.w = w.y - w.w;

        // FWHT stages j^4 .. j^128: lane xor 1,2,4,8,16,32
        #pragma unroll
        for (int s = 0; s < 6; ++s) {
            const int mask = 1 << s;
            float4 o;
            o.x = __shfl_xor(v.x, mask, 64);
            o.y = __shfl_xor(v.y, mask, 64);
            o.z = __shfl_xor(v.z, mask, 64);
            o.w = __shfl_xor(v.w, mask, 64);
            // low lane: u+v ; high lane: u-v = other - mine
            const float sgn = 1.0f - 2.0f * (float)((lane >> s) & 1);
            v.x = fmaf(sgn, v.x, o.x);
            v.y = fmaf(sgn, v.y, o.y);
            v.z = fmaf(sgn, v.z, o.z);
            v.w = fmaf(sgn, v.w, o.w);
        }

        // scale by (1/sqrt2)^8 = 1/16, scatter to freq-ordered LDS row
        lds[kl][freq_pos(4 * lane + 0)] = v.x * 0.0625f;
        lds[kl][freq_pos(4 * lane + 1)] = v.y * 0.0625f;
        lds[kl][freq_pos(4 * lane + 2)] = v.z * 0.0625f;
        lds[kl][freq_pos(4 * lane + 3)] = v.w * 0.0625f;
    }
    __syncthreads();

    // Transposed, coalesced write: coeffs[b][m][k0 + kk .. kk+3]
    float* ob = coeffs + (size_t)b * T + k0;
    const int kk = (threadIdx.x & 7) * 4; // k offset within group
    const int m0 = threadIdx.x >> 3;      // 0..31
    #pragma unroll
    for (int p = 0; p < 8; ++p) {
        const int m = p * 32 + m0;
        float4 v;
        v.x = lds[kk + 0][m];
        v.y = lds[kk + 1][m];
        v.z = lds[kk + 2][m];
        v.w = lds[kk + 3][m];
        *(float4*)(ob + (size_t)m * NCH + kk) = v;
    }
}

__global__ __launch_bounds__(256) void entropy_kernel(float* __restrict__ coeffs,
                                                      float* __restrict__ entropy,
                                                      float* __restrict__ keep) {
    const int lane = threadIdx.x & 63;
    const int wave = threadIdx.x >> 6;
    const int row  = blockIdx.x * 4 + wave; // row = b*NODES + n, 0..32767

    float* cp = coeffs + (size_t)row * NCH;
    float4 v = *(const float4*)(cp + lane * 4);

    float4 sq;
    sq.x = v.x * v.x; sq.y = v.y * v.y;
    sq.z = v.z * v.z; sq.w = v.w * v.w;

    float s = sq.x + sq.y + sq.z + sq.w;
    #pragma unroll
    for (int m = 1; m < 64; m <<= 1) s += __shfl_xor(s, m, 64);

    const float inv = 1.0f / (s + 1e-8f);
    const float p0 = sq.x * inv, p1 = sq.y * inv, p2 = sq.z * inv, p3 = sq.w * inv;
    float t = p0 * logf(p0 + 1e-8f) + p1 * logf(p1 + 1e-8f)
            + p2 * logf(p2 + 1e-8f) + p3 * logf(p3 + 1e-8f);
    #pragma unroll
    for (int m = 1; m < 64; m <<= 1) t += __shfl_xor(t, m, 64);

    const float e  = -t;
    const bool  kp = e > 0.1f;

    if (!kp) {
        *(float4*)(cp + lane * 4) = make_float4(0.f, 0.f, 0.f, 0.f);
    }
    if (lane == 0) {
        entropy[row] = e;
        keep[row]    = kp ? 1.0f : 0.0f;
    }
}

extern "C" void kernel_launch(void* const* d_in, const int* in_sizes, int n_in,
                              void* d_out, int out_size, void* d_ws, size_t ws_size,
                              hipStream_t stream) {
    const float* x = (const float*)d_in[0];

    float* coeffs  = (float*)d_out;                                // [128][256][256]
    float* entropy = coeffs + (size_t)BROWS * NODES * NCH;         // [128][256]
    float* keepf   = entropy + (size_t)BROWS * NODES;              // [128][256] as 0/1 float

    wht_kernel<<<dim3(BROWS * (NCH / KG)), dim3(256), 0, stream>>>(x, coeffs);
    entropy_kernel<<<dim3(BROWS * NODES / 4), dim3(256), 0, stream>>>(coeffs, entropy, keepf);
}

// Round 3
// 88.406 us; speedup vs baseline: 1.0486x; 1.0486x over previous
//
#include <hip/hip_runtime.h>

// Problem constants (x: [128, 65536] fp32, LEVEL=8)
static constexpr int BROWS = 128;   // batch rows
static constexpr int T     = 65536; // samples per row
static constexpr int CL    = 256;   // chunk length = 2^LEVEL
static constexpr int NCH   = 256;   // chunks per row = T / CL (positions per node)
static constexpr int NODES = 256;   // 2^LEVEL leaves
static constexpr int KG    = 32;    // chunks handled per block in wht_kernel
static constexpr int LSTR  = 257;   // padded LDS row stride (breaks bank conflicts)

typedef float nfloat4 __attribute__((ext_vector_type(4))); // native vec for nontemporal builtin

// Output row for Hadamard-order index h:
//   c_nat[n] = H[bitrev8(n)],  freq perm: out[m] = c_nat[gray^-1(m)]
//   => m = gray(bitrev8(h))
__device__ __forceinline__ int freq_pos(int h) {
    unsigned r = __brev((unsigned)h) >> 24; // bitrev8
    return (int)(r ^ (r >> 1));             // gray code
}

// Per block: 32 chunks of one batch row -> FWHT -> freq-ordered transposed
// coeffs write + per-node partial (A = sum c^2, B = sum c^2 log c^2) into ws.
__global__ __launch_bounds__(256) void wht_kernel(const float* __restrict__ x,
                                                  float* __restrict__ coeffs,
                                                  float* __restrict__ part) {
    __shared__ float lds[KG][LSTR]; // 32.9 KB; reused as 4x2x256 partial buffer later

    const int b    = blockIdx.x >> 3;  // 8 chunk-groups per row
    const int kg   = blockIdx.x & 7;
    const int k0   = kg * KG;
    const int lane = threadIdx.x & 63;
    const int wave = threadIdx.x >> 6; // 4 waves

    const float* xb = x + (size_t)b * T;

    // lane l owns the SAME 4 nodes in every chunk -> register accumulation
    int npos[4];
    #pragma unroll
    for (int i = 0; i < 4; ++i) npos[i] = freq_pos(4 * lane + i);
    float regA[4] = {0.f, 0.f, 0.f, 0.f};
    float regB[4] = {0.f, 0.f, 0.f, 0.f};

    // Each wave computes 8 chunks; lane holds elements j = 4*lane + {0,1,2,3}
    #pragma unroll
    for (int c = 0; c < KG / 4; ++c) {
        const int kl = wave * (KG / 4) + c; // local chunk row in LDS
        float4 v = *(const float4*)(xb + (size_t)(k0 + kl) * CL + lane * 4);

        // FWHT stage j^1 (intra-lane)
        float4 w;
        w.x = v.x + v.y; w.y = v.x - v.y;
        w.z = v.z + v.w; w.w = v.z - v.w;
        // FWHT stage j^2 (intra-lane)
        v.x = w.x + w.z; v.z = w.x - w.z;
        v.y = w.y + w.w; v.w = w.y - w.w;

        // FWHT stages j^4 .. j^128: lane xor 1,2,4,8,16,32
        #pragma unroll
        for (int s = 0; s < 6; ++s) {
            const int mask = 1 << s;
            float4 o;
            o.x = __shfl_xor(v.x, mask, 64);
            o.y = __shfl_xor(v.y, mask, 64);
            o.z = __shfl_xor(v.z, mask, 64);
            o.w = __shfl_xor(v.w, mask, 64);
            const float sgn = 1.0f - 2.0f * (float)((lane >> s) & 1);
            v.x = fmaf(sgn, v.x, o.x);
            v.y = fmaf(sgn, v.y, o.y);
            v.z = fmaf(sgn, v.z, o.z);
            v.w = fmaf(sgn, v.w, o.w);
        }

        // scale by (1/sqrt2)^8 = 1/16; accumulate entropy partials; LDS scatter
        float cv[4] = {v.x * 0.0625f, v.y * 0.0625f, v.z * 0.0625f, v.w * 0.0625f};
        #pragma unroll
        for (int i = 0; i < 4; ++i) {
            const float s2 = cv[i] * cv[i];
            regA[i] += s2;
            regB[i] += s2 * __logf(s2 + 1e-35f); // c=0 -> term 0, matches p*log(p+eps)
            lds[kl][npos[i]] = cv[i];
        }
    }
    __syncthreads();

    // Transposed, coalesced write: coeffs[b][m][k0 + kk .. kk+3] (write-once -> nontemporal)
    float* ob = coeffs + (size_t)b * T + k0;
    const int kk = (threadIdx.x & 7) * 4; // k offset within group
    const int m0 = threadIdx.x >> 3;      // 0..31
    #pragma unroll
    for (int p = 0; p < 8; ++p) {
        const int m = p * 32 + m0;
        nfloat4 v;
        v.x = lds[kk + 0][m];
        v.y = lds[kk + 1][m];
        v.z = lds[kk + 2][m];
        v.w = lds[kk + 3][m];
        __builtin_nontemporal_store(v, (nfloat4*)(ob + (size_t)m * NCH + kk));
    }
    __syncthreads();

    // Cross-wave reduction of per-node partials (reuse lds as flat buffer)
    float* pl = &lds[0][0]; // need 4*512 = 2048 floats, have 8224
    #pragma unroll
    for (int i = 0; i < 4; ++i) {
        pl[wave * 512 + npos[i]]       = regA[i];
        pl[wave * 512 + 256 + npos[i]] = regB[i];
    }
    __syncthreads();

    const int n = threadIdx.x; // 0..255 = node
    const float A = pl[n] + pl[512 + n] + pl[1024 + n] + pl[1536 + n];
    const float B = pl[256 + n] + pl[768 + n] + pl[1280 + n] + pl[1792 + n];
    float* pp = part + (size_t)blockIdx.x * 512;
    pp[n]       = A;
    pp[256 + n] = B;
}

// One thread per (b, n): sum the 8 block-partials, entropy = (A*logS - B)/S,
// S = A + 1e-8. Zero the coeff row only when !keep (rare).
__global__ __launch_bounds__(256) void finalize_kernel(const float* __restrict__ part,
                                                       float* __restrict__ coeffs,
                                                       float* __restrict__ entropy,
                                                       float* __restrict__ keep) {
    const int row = blockIdx.x * 256 + threadIdx.x; // b*256 + n
    const int b = row >> 8;
    const int n = row & 255;

    float A = 0.f, B = 0.f;
    #pragma unroll
    for (int g = 0; g < 8; ++g) {
        const float* p = part + (size_t)(b * 8 + g) * 512;
        A += p[n];
        B += p[256 + n];
    }

    const float S = A + 1e-8f;
    const float e = (A * __logf(S) - B) / S;
    const bool kp = e > 0.1f;

    entropy[row] = e;
    keep[row]    = kp ? 1.0f : 0.0f;

    if (!kp) {
        float4 z = make_float4(0.f, 0.f, 0.f, 0.f);
        float4* cp = (float4*)(coeffs + (size_t)row * NCH);
        #pragma unroll
        for (int j = 0; j < NCH / 4; ++j) cp[j] = z;
    }
}

extern "C" void kernel_launch(void* const* d_in, const int* in_sizes, int n_in,
                              void* d_out, int out_size, void* d_ws, size_t ws_size,
                              hipStream_t stream) {
    const float* x = (const float*)d_in[0];

    float* coeffs  = (float*)d_out;                         // [128][256][256]
    float* entropy = coeffs + (size_t)BROWS * NODES * NCH;  // [128][256]
    float* keepf   = entropy + (size_t)BROWS * NODES;       // [128][256] as 0/1 float

    float* part = (float*)d_ws; // [1024 blocks][2][256] = 2 MB

    wht_kernel<<<dim3(BROWS * (NCH / KG)), dim3(256), 0, stream>>>(x, coeffs, part);
    finalize_kernel<<<dim3(BROWS * NODES / 256), dim3(256), 0, stream>>>(part, coeffs, entropy, keepf);
}

// Round 4
// 87.196 us; speedup vs baseline: 1.0631x; 1.0139x over previous
//
#include <hip/hip_runtime.h>

// Problem constants (x: [128, 65536] fp32, LEVEL=8)
static constexpr int BROWS = 128;   // batch rows
static constexpr int T     = 65536; // samples per row
static constexpr int CL    = 256;   // chunk length = 2^LEVEL
static constexpr int NCH   = 256;   // chunks per row = T / CL (positions per node)
static constexpr int NODES = 256;   // 2^LEVEL leaves
static constexpr int KG    = 32;    // chunks handled per block in wht_kernel
static constexpr int LSTR  = 257;   // padded LDS row stride (breaks bank conflicts)

// Output row for Hadamard-order index h (in-place FWHT leaves Hadamard order):
//   c_nat[n] = H[bitrev8(n)], freq perm out[m] = c_nat[gray^-1(m)] => m = gray(bitrev8(h))
__device__ __forceinline__ int freq_pos(int h) {
    unsigned r = __brev((unsigned)h) >> 24; // bitrev8
    return (int)(r ^ (r >> 1));             // gray code
}

__device__ __forceinline__ void bfly01(float4& v) {
    // FWHT stages on j-bits 0,1 (within the float4)
    float4 w;
    w.x = v.x + v.y; w.y = v.x - v.y;
    w.z = v.z + v.w; w.w = v.z - v.w;
    v.x = w.x + w.z; v.z = w.x - w.z;
    v.y = w.y + w.w; v.w = w.y - w.w;
}

// Per block: 32 chunks of one batch row -> 256-pt FWHT (dual-chunk wave layout)
// -> freq-ordered transposed coeffs write + per-node entropy partials into ws.
__global__ __launch_bounds__(256) void wht_kernel(const float* __restrict__ x,
                                                  float* __restrict__ coeffs,
                                                  float* __restrict__ part) {
    __shared__ float lds[KG][LSTR]; // 32.9 KB; reused as 4x2x256 partial buffer later

    const int b    = blockIdx.x >> 3;  // 8 chunk-groups per row
    const int kg   = blockIdx.x & 7;
    const int k0   = kg * KG;
    const int lane = threadIdx.x & 63;
    const int wave = threadIdx.x >> 6; // 4 waves
    const int half = lane >> 5;        // which of 2 concurrent chunks
    const int L    = lane & 31;        // position within chunk (j-bits 2..6)

    const float* xb = x + (size_t)b * T;

    // lane owns the SAME 8 nodes (h = 4L+i and 128+4L+i) in every chunk
    int npos1[4], npos2[4];
    #pragma unroll
    for (int i = 0; i < 4; ++i) {
        npos1[i] = freq_pos(4 * L + i);
        npos2[i] = freq_pos(128 + 4 * L + i);
    }
    float A1[4] = {0.f,0.f,0.f,0.f}, B1[4] = {0.f,0.f,0.f,0.f};
    float A2[4] = {0.f,0.f,0.f,0.f}, B2[4] = {0.f,0.f,0.f,0.f};

    // Each wave handles 8 chunks as 4 iterations x 2 chunks (one per lane-half)
    #pragma unroll
    for (int it = 0; it < 4; ++it) {
        const int kl = wave * 8 + it * 2 + half; // local chunk row in LDS
        const float* cp = xb + (size_t)(k0 + kl) * CL + 4 * L;
        float4 v1 = *(const float4*)(cp);        // j = 4L+i      (bit7=0)
        float4 v2 = *(const float4*)(cp + 128);  // j = 128+4L+i  (bit7=1)

        // FWHT stage j-bit7 (across the two registers, pure VALU)
        float4 t;
        t.x = v1.x - v2.x; t.y = v1.y - v2.y; t.z = v1.z - v2.z; t.w = v1.w - v2.w;
        v1.x += v2.x; v1.y += v2.y; v1.z += v2.z; v1.w += v2.w;
        v2 = t;

        // FWHT stages j-bits 0,1 (intra-float4)
        bfly01(v1);
        bfly01(v2);

        // FWHT stages j-bits 2..6: lane xor 1,2,4,8,16 (stays within 32-lane half)
        #pragma unroll
        for (int s = 0; s < 5; ++s) {
            const int mask = 1 << s;
            const float sgn = 1.0f - 2.0f * (float)((L >> s) & 1);
            float o;
            o = __shfl_xor(v1.x, mask, 64); v1.x = fmaf(sgn, v1.x, o);
            o = __shfl_xor(v1.y, mask, 64); v1.y = fmaf(sgn, v1.y, o);
            o = __shfl_xor(v1.z, mask, 64); v1.z = fmaf(sgn, v1.z, o);
            o = __shfl_xor(v1.w, mask, 64); v1.w = fmaf(sgn, v1.w, o);
            o = __shfl_xor(v2.x, mask, 64); v2.x = fmaf(sgn, v2.x, o);
            o = __shfl_xor(v2.y, mask, 64); v2.y = fmaf(sgn, v2.y, o);
            o = __shfl_xor(v2.z, mask, 64); v2.z = fmaf(sgn, v2.z, o);
            o = __shfl_xor(v2.w, mask, 64); v2.w = fmaf(sgn, v2.w, o);
        }

        // scale by (1/sqrt2)^8 = 1/16; accumulate entropy partials; LDS scatter
        float c1[4] = {v1.x*0.0625f, v1.y*0.0625f, v1.z*0.0625f, v1.w*0.0625f};
        float c2[4] = {v2.x*0.0625f, v2.y*0.0625f, v2.z*0.0625f, v2.w*0.0625f};
        #pragma unroll
        for (int i = 0; i < 4; ++i) {
            const float s1 = c1[i] * c1[i];
            A1[i] += s1;
            B1[i] += s1 * __logf(s1 + 1e-35f); // c=0 -> term 0, matches p*log(p+eps)
            lds[kl][npos1[i]] = c1[i];
            const float s2 = c2[i] * c2[i];
            A2[i] += s2;
            B2[i] += s2 * __logf(s2 + 1e-35f);
            lds[kl][npos2[i]] = c2[i];
        }
    }
    __syncthreads();

    // Transposed, coalesced write: coeffs[b][m][k0 + kk .. kk+3]
    float* ob = coeffs + (size_t)b * T + k0;
    const int kk = (threadIdx.x & 7) * 4; // k offset within group
    const int m0 = threadIdx.x >> 3;      // 0..31
    #pragma unroll
    for (int p = 0; p < 8; ++p) {
        const int m = p * 32 + m0;
        float4 v;
        v.x = lds[kk + 0][m];
        v.y = lds[kk + 1][m];
        v.z = lds[kk + 2][m];
        v.w = lds[kk + 3][m];
        *(float4*)(ob + (size_t)m * NCH + kk) = v;
    }
    __syncthreads();

    // Merge the two lane-halves (same node sets), then cross-wave reduce via LDS
    #pragma unroll
    for (int i = 0; i < 4; ++i) {
        A1[i] += __shfl_xor(A1[i], 32, 64); B1[i] += __shfl_xor(B1[i], 32, 64);
        A2[i] += __shfl_xor(A2[i], 32, 64); B2[i] += __shfl_xor(B2[i], 32, 64);
    }
    float* pl = &lds[0][0]; // need 4*512 = 2048 floats, have 8224
    if (half == 0) {
        #pragma unroll
        for (int i = 0; i < 4; ++i) {
            pl[wave * 512 + npos1[i]]       = A1[i];
            pl[wave * 512 + 256 + npos1[i]] = B1[i];
            pl[wave * 512 + npos2[i]]       = A2[i];
            pl[wave * 512 + 256 + npos2[i]] = B2[i];
        }
    }
    __syncthreads();

    const int n = threadIdx.x; // 0..255 = node
    const float A = pl[n] + pl[512 + n] + pl[1024 + n] + pl[1536 + n];
    const float B = pl[256 + n] + pl[768 + n] + pl[1280 + n] + pl[1792 + n];
    float* pp = part + (size_t)blockIdx.x * 512;
    pp[n]       = A;
    pp[256 + n] = B;
}

// One thread per (b, n): sum the 8 block-partials, entropy = (A*logS - B)/S,
// S = A + 1e-8. Zero the coeff row only when !keep (rare for Gaussian input).
__global__ __launch_bounds__(256) void finalize_kernel(const float* __restrict__ part,
                                                       float* __restrict__ coeffs,
                                                       float* __restrict__ entropy,
                                                       float* __restrict__ keep) {
    const int row = blockIdx.x * 256 + threadIdx.x; // b*256 + n
    const int b = row >> 8;
    const int n = row & 255;

    float A = 0.f, B = 0.f;
    #pragma unroll
    for (int g = 0; g < 8; ++g) {
        const float* p = part + (size_t)(b * 8 + g) * 512;
        A += p[n];
        B += p[256 + n];
    }

    const float S = A + 1e-8f;
    const float e = (A * __logf(S) - B) / S;
    const bool kp = e > 0.1f;

    entropy[row] = e;
    keep[row]    = kp ? 1.0f : 0.0f;

    if (!kp) {
        float4 z = make_float4(0.f, 0.f, 0.f, 0.f);
        float4* cp = (float4*)(coeffs + (size_t)row * NCH);
        #pragma unroll
        for (int j = 0; j < NCH / 4; ++j) cp[j] = z;
    }
}

extern "C" void kernel_launch(void* const* d_in, const int* in_sizes, int n_in,
                              void* d_out, int out_size, void* d_ws, size_t ws_size,
                              hipStream_t stream) {
    const float* x = (const float*)d_in[0];

    float* coeffs  = (float*)d_out;                         // [128][256][256]
    float* entropy = coeffs + (size_t)BROWS * NODES * NCH;  // [128][256]
    float* keepf   = entropy + (size_t)BROWS * NODES;       // [128][256] as 0/1 float

    float* part = (float*)d_ws; // [1024 blocks][2][256] = 2 MB

    wht_kernel<<<dim3(BROWS * (NCH / KG)), dim3(256), 0, stream>>>(x, coeffs, part);
    finalize_kernel<<<dim3(BROWS * NODES / 256), dim3(256), 0, stream>>>(part, coeffs, entropy, keepf);
}

// Round 5
// 85.233 us; speedup vs baseline: 1.0876x; 1.0230x over previous
//
#include <hip/hip_runtime.h>

// Problem constants (x: [128, 65536] fp32, LEVEL=8)
static constexpr int BROWS = 128;   // batch rows
static constexpr int T     = 65536; // samples per row
static constexpr int CL    = 256;   // chunk length = 2^LEVEL
static constexpr int NCH   = 256;   // chunks per row = T / CL (positions per node)
static constexpr int NODES = 256;   // 2^LEVEL leaves
static constexpr int KG    = 32;    // chunks handled per block in wht_kernel
static constexpr int LSTR  = 257;   // padded LDS row stride (breaks bank conflicts)

// Output row for Hadamard-order index h (in-place FWHT leaves Hadamard order):
//   c_nat[n] = H[bitrev8(n)], freq perm out[m] = c_nat[gray^-1(m)] => m = gray(bitrev8(h))
__device__ __forceinline__ int freq_pos(int h) {
    unsigned r = __brev((unsigned)h) >> 24; // bitrev8
    return (int)(r ^ (r >> 1));             // gray code
}

__device__ __forceinline__ void bfly01(float4& v) {
    // FWHT stages on j-bits 0,1 (within the float4)
    float4 w;
    w.x = v.x + v.y; w.y = v.x - v.y;
    w.z = v.z + v.w; w.w = v.z - v.w;
    v.x = w.x + w.z; v.z = w.x - w.z;
    v.y = w.y + w.w; v.w = w.y - w.w;
}

// Lane-exchange via DPP (VALU pipe — no LDS traffic).
// xor1 = quad_perm [1,0,3,2] = 0xB1; xor2 = quad_perm [2,3,0,1] = 0x4E;
// xor8 = row_ror:8 = 0x128 ((i+8)%16 == i^8 within a 16-lane row).
template<int CTRL>
__device__ __forceinline__ float xchg_dpp(float v) {
    return __builtin_bit_cast(float,
        __builtin_amdgcn_update_dpp(0, __builtin_bit_cast(int, v), CTRL, 0xF, 0xF, true));
}

template<int CTRL>
__device__ __forceinline__ void stage_dpp(float4& v1, float4& v2, float sgn) {
    float o;
    o = xchg_dpp<CTRL>(v1.x); v1.x = fmaf(sgn, v1.x, o);
    o = xchg_dpp<CTRL>(v1.y); v1.y = fmaf(sgn, v1.y, o);
    o = xchg_dpp<CTRL>(v1.z); v1.z = fmaf(sgn, v1.z, o);
    o = xchg_dpp<CTRL>(v1.w); v1.w = fmaf(sgn, v1.w, o);
    o = xchg_dpp<CTRL>(v2.x); v2.x = fmaf(sgn, v2.x, o);
    o = xchg_dpp<CTRL>(v2.y); v2.y = fmaf(sgn, v2.y, o);
    o = xchg_dpp<CTRL>(v2.z); v2.z = fmaf(sgn, v2.z, o);
    o = xchg_dpp<CTRL>(v2.w); v2.w = fmaf(sgn, v2.w, o);
}

__device__ __forceinline__ void stage_shfl(float4& v1, float4& v2, float sgn, int mask) {
    float o;
    o = __shfl_xor(v1.x, mask, 64); v1.x = fmaf(sgn, v1.x, o);
    o = __shfl_xor(v1.y, mask, 64); v1.y = fmaf(sgn, v1.y, o);
    o = __shfl_xor(v1.z, mask, 64); v1.z = fmaf(sgn, v1.z, o);
    o = __shfl_xor(v1.w, mask, 64); v1.w = fmaf(sgn, v1.w, o);
    o = __shfl_xor(v2.x, mask, 64); v2.x = fmaf(sgn, v2.x, o);
    o = __shfl_xor(v2.y, mask, 64); v2.y = fmaf(sgn, v2.y, o);
    o = __shfl_xor(v2.z, mask, 64); v2.z = fmaf(sgn, v2.z, o);
    o = __shfl_xor(v2.w, mask, 64); v2.w = fmaf(sgn, v2.w, o);
}

// Per block: 32 chunks of one batch row -> 256-pt FWHT (dual-chunk wave layout)
// -> freq-ordered transposed coeffs write + per-node entropy partials into ws.
__global__ __launch_bounds__(256) void wht_kernel(const float* __restrict__ x,
                                                  float* __restrict__ coeffs,
                                                  float* __restrict__ part) {
    __shared__ float lds[KG][LSTR]; // 32.9 KB; reused as 4x2x256 partial buffer later

    const int b    = blockIdx.x >> 3;  // 8 chunk-groups per row
    const int kg   = blockIdx.x & 7;
    const int k0   = kg * KG;
    const int lane = threadIdx.x & 63;
    const int wave = threadIdx.x >> 6; // 4 waves
    const int half = lane >> 5;        // which of 2 concurrent chunks
    const int L    = lane & 31;        // position within chunk (j-bits 2..6)

    const float* xb = x + (size_t)b * T;

    // lane owns the SAME 8 nodes (h = 4L+i and 128+4L+i) in every chunk
    int npos1[4], npos2[4];
    #pragma unroll
    for (int i = 0; i < 4; ++i) {
        npos1[i] = freq_pos(4 * L + i);
        npos2[i] = freq_pos(128 + 4 * L + i);
    }
    float A1[4] = {0.f,0.f,0.f,0.f}, B1[4] = {0.f,0.f,0.f,0.f};
    float A2[4] = {0.f,0.f,0.f,0.f}, B2[4] = {0.f,0.f,0.f,0.f};

    // Butterfly signs for the 5 cross-lane stages (loop-invariant)
    const float sgn0 = 1.0f - 2.0f * (float)((L >> 0) & 1);
    const float sgn1 = 1.0f - 2.0f * (float)((L >> 1) & 1);
    const float sgn2 = 1.0f - 2.0f * (float)((L >> 2) & 1);
    const float sgn3 = 1.0f - 2.0f * (float)((L >> 3) & 1);
    const float sgn4 = 1.0f - 2.0f * (float)((L >> 4) & 1);

    // Each wave handles 8 chunks as 4 iterations x 2 chunks (one per lane-half)
    #pragma unroll
    for (int it = 0; it < 4; ++it) {
        const int kl = wave * 8 + it * 2 + half; // local chunk row in LDS
        const float* cp = xb + (size_t)(k0 + kl) * CL + 4 * L;
        float4 v1 = *(const float4*)(cp);        // j = 4L+i      (bit7=0)
        float4 v2 = *(const float4*)(cp + 128);  // j = 128+4L+i  (bit7=1)

        // FWHT stage j-bit7 (across the two registers, pure VALU)
        float4 t;
        t.x = v1.x - v2.x; t.y = v1.y - v2.y; t.z = v1.z - v2.z; t.w = v1.w - v2.w;
        v1.x += v2.x; v1.y += v2.y; v1.z += v2.z; v1.w += v2.w;
        v2 = t;

        // FWHT stages j-bits 0,1 (intra-float4)
        bfly01(v1);
        bfly01(v2);

        // FWHT stages j-bits 2..6 = lane xor 1,2,4,8,16.
        // Masks 1,2,8 run on the VALU via DPP; masks 4,16 stay on the LDS pipe.
        stage_dpp<0xB1>(v1, v2, sgn0);   // xor 1  (quad_perm [1,0,3,2])
        stage_dpp<0x4E>(v1, v2, sgn1);   // xor 2  (quad_perm [2,3,0,1])
        stage_shfl(v1, v2, sgn2, 4);     // xor 4  (ds_swizzle)
        stage_dpp<0x128>(v1, v2, sgn3);  // xor 8  (row_ror:8)
        stage_shfl(v1, v2, sgn4, 16);    // xor 16 (ds_swizzle)

        // scale by (1/sqrt2)^8 = 1/16; accumulate entropy partials; LDS scatter
        float c1[4] = {v1.x*0.0625f, v1.y*0.0625f, v1.z*0.0625f, v1.w*0.0625f};
        float c2[4] = {v2.x*0.0625f, v2.y*0.0625f, v2.z*0.0625f, v2.w*0.0625f};
        #pragma unroll
        for (int i = 0; i < 4; ++i) {
            const float s1 = c1[i] * c1[i];
            A1[i] += s1;
            B1[i] += s1 * __logf(s1 + 1e-35f); // c=0 -> term 0, matches p*log(p+eps)
            lds[kl][npos1[i]] = c1[i];
            const float s2 = c2[i] * c2[i];
            A2[i] += s2;
            B2[i] += s2 * __logf(s2 + 1e-35f);
            lds[kl][npos2[i]] = c2[i];
        }
    }
    __syncthreads();

    // Transposed, coalesced write: coeffs[b][m][k0 + kk .. kk+3]
    float* ob = coeffs + (size_t)b * T + k0;
    const int kk = (threadIdx.x & 7) * 4; // k offset within group
    const int m0 = threadIdx.x >> 3;      // 0..31
    #pragma unroll
    for (int p = 0; p < 8; ++p) {
        const int m = p * 32 + m0;
        float4 v;
        v.x = lds[kk + 0][m];
        v.y = lds[kk + 1][m];
        v.z = lds[kk + 2][m];
        v.w = lds[kk + 3][m];
        *(float4*)(ob + (size_t)m * NCH + kk) = v;
    }
    __syncthreads();

    // Merge the two lane-halves (same node sets), then cross-wave reduce via LDS
    #pragma unroll
    for (int i = 0; i < 4; ++i) {
        A1[i] += __shfl_xor(A1[i], 32, 64); B1[i] += __shfl_xor(B1[i], 32, 64);
        A2[i] += __shfl_xor(A2[i], 32, 64); B2[i] += __shfl_xor(B2[i], 32, 64);
    }
    float* pl = &lds[0][0]; // need 4*512 = 2048 floats, have 8224
    if (half == 0) {
        #pragma unroll
        for (int i = 0; i < 4; ++i) {
            pl[wave * 512 + npos1[i]]       = A1[i];
            pl[wave * 512 + 256 + npos1[i]] = B1[i];
            pl[wave * 512 + npos2[i]]       = A2[i];
            pl[wave * 512 + 256 + npos2[i]] = B2[i];
        }
    }
    __syncthreads();

    const int n = threadIdx.x; // 0..255 = node
    const float A = pl[n] + pl[512 + n] + pl[1024 + n] + pl[1536 + n];
    const float B = pl[256 + n] + pl[768 + n] + pl[1280 + n] + pl[1792 + n];
    float* pp = part + (size_t)blockIdx.x * 512;
    pp[n]       = A;
    pp[256 + n] = B;
}

// One thread per (b, n): sum the 8 block-partials, entropy = (A*logS - B)/S,
// S = A + 1e-8. Zero the coeff row only when !keep (rare for Gaussian input).
__global__ __launch_bounds__(256) void finalize_kernel(const float* __restrict__ part,
                                                       float* __restrict__ coeffs,
                                                       float* __restrict__ entropy,
                                                       float* __restrict__ keep) {
    const int row = blockIdx.x * 256 + threadIdx.x; // b*256 + n
    const int b = row >> 8;
    const int n = row & 255;

    float A = 0.f, B = 0.f;
    #pragma unroll
    for (int g = 0; g < 8; ++g) {
        const float* p = part + (size_t)(b * 8 + g) * 512;
        A += p[n];
        B += p[256 + n];
    }

    const float S = A + 1e-8f;
    const float e = (A * __logf(S) - B) / S;
    const bool kp = e > 0.1f;

    entropy[row] = e;
    keep[row]    = kp ? 1.0f : 0.0f;

    if (!kp) {
        float4 z = make_float4(0.f, 0.f, 0.f, 0.f);
        float4* cp = (float4*)(coeffs + (size_t)row * NCH);
        #pragma unroll
        for (int j = 0; j < NCH / 4; ++j) cp[j] = z;
    }
}

extern "C" void kernel_launch(void* const* d_in, const int* in_sizes, int n_in,
                              void* d_out, int out_size, void* d_ws, size_t ws_size,
                              hipStream_t stream) {
    const float* x = (const float*)d_in[0];

    float* coeffs  = (float*)d_out;                         // [128][256][256]
    float* entropy = coeffs + (size_t)BROWS * NODES * NCH;  // [128][256]
    float* keepf   = entropy + (size_t)BROWS * NODES;       // [128][256] as 0/1 float

    float* part = (float*)d_ws; // [1024 blocks][2][256] = 2 MB

    wht_kernel<<<dim3(BROWS * (NCH / KG)), dim3(256), 0, stream>>>(x, coeffs, part);
    finalize_kernel<<<dim3(BROWS * NODES / 256), dim3(256), 0, stream>>>(part, coeffs, entropy, keepf);
}